// Round 9
// baseline (396.137 us; speedup 1.0000x reference)
//
#include <hip/hip_runtime.h>
#include <stdint.h>

#define H 192
#define W 192
#define CIN 32
#define NOUT 32
#define NB 16
#define PADI 4

#define HT 16          // output rows per tile
#define WTL 16         // output cols per tile
#define RROWS 24       // HT + 8 halo
#define RCOLS 24       // WTL + 8 halo
#define NTILES (NB * (H / HT) * (W / WTL))   // 2304
#define NBLK 512       // persistent blocks: 2/CU guaranteed by launch_bounds(256,2)
#define TPX (NTILES / 8)                     // 288 tiles per XCD class = 2 whole images

typedef __attribute__((ext_vector_type(8))) short bf16x8;
typedef __attribute__((ext_vector_type(4))) float f32x4;

__device__ __forceinline__ unsigned short f2bf(float f) {
    union { float f; unsigned int u; } v; v.f = f;
    unsigned int r = v.u + 0x7fffu + ((v.u >> 16) & 1u);
    return (unsigned short)(r >> 16);
}

// HW round-to-nearest-even pack of 2 f32 -> 2 bf16 in one VALU op.
__device__ __forceinline__ unsigned int cvtpk_bf16(float lo, float hi) {
    unsigned int r;
    asm("v_cvt_pk_bf16_f32 %0, %1, %2" : "=v"(r) : "v"(lo), "v"(hi));
    return r;
}

// ---- Gaussian kernel generation (proven) ----
// W2g[mt][tap][quad][m][j]  (mt=o>>4, m=o&15, quad=i>>3, j=i&7)
__global__ void genw_kernel(const float* __restrict__ wp, unsigned short* __restrict__ W2g) {
    const int b = blockIdx.x;          // = o*32 + i
    const int o = b >> 5;
    const int i = b & 31;
    const int t = threadIdx.x;         // 0..127

    float sx = wp[b * 3 + 0], sy = wp[b * 3 + 1], th = wp[b * 3 + 2];
    float rad = th / 180.0f * 3.14159265358979323846f;
    float co = cosf(rad), si = sinf(rad);
    float sx2 = sx * sx, sy2 = sy * sy;
    float a = co * co * sx2 + si * si * sy2;
    float bb = co * si * (sx2 - sy2);
    float d = si * si * sx2 + co * co * sy2;
    float det = a * d - bb * bb;
    float ia = d / det, ib = -bb / det, idd = a / det;

    const int tap = t;
    float e = 0.0f;
    if (tap < 81) {
        float xx = (float)(tap % 9 - 4);
        float yy = (float)(tap / 9 - 4);
        float q = ia * xx * xx + 2.0f * ib * xx * yy + idd * yy * yy;
        e = expf(-0.5f * q);
    }
    float s = e;
    #pragma unroll
    for (int off = 32; off > 0; off >>= 1) s += __shfl_down(s, off);
    __shared__ float ws[2];
    if ((t & 63) == 0) ws[t >> 6] = s;
    __syncthreads();
    float total = ws[0] + ws[1];

    if (tap < 81) {
        int mt = o >> 4, m = o & 15, quad = i >> 3, j = i & 7;
        W2g[((((mt * 81 + tap) * 4 + quad) * 16 + m) << 3) + j] = f2bf(e / total);
    }
}

// ---- Persistent conv: cross-tile T14 reg-prefetch, no pre-pass ----
// 512 blocks x 256 thr (4 waves), 2 blocks/CU. Block handles 4-5 CONTIGUOUS
// tiles of its XCD class (class c = tiles [288c, 288(c+1)) = 2 whole images:
// preserves L2 locality, the R4 failure). Per tile:
//   pack v->LDS (cvt_pk), A-preload, barrier,
//   issue next tile's 72 VOLATILE fp32 loads (volatile = LLVM cannot sink
//   them to first use, defeating the R0/R6 re-serialization),
//   champion dx-loop (A[2][9] dbuf, setprio, bias-in-acc), store, barrier.
// Next-tile HBM latency hides under ~6300 cyc of MFMA. Only tile 0 exposed.
__global__ __launch_bounds__(256, 2) void conv_kernel(
    const float* __restrict__ x, const unsigned short* __restrict__ W2g,
    const float* __restrict__ bias, float* __restrict__ out)
{
    __shared__ __align__(16) unsigned short ldsx[4 * RROWS * RCOLS * 8];  // 36,864 B

    const int t = threadIdx.x;
    const int xcd  = blockIdx.x & 7;
    const int slot = blockIdx.x >> 3;     // 0..63
    int t0, cnt;
    if (slot < 32) { cnt = 5; t0 = xcd * TPX + slot * 5; }           // 32*5=160
    else           { cnt = 4; t0 = xcd * TPX + 160 + (slot - 32) * 4; } // 32*4=128

    const int wave = t >> 6;
    const int lane = t & 63;
    const int l15 = lane & 15;      // A: m-row / B: pixel col / D: col
    const int quad4 = lane >> 4;    // A/B: k-group (8 ch) / D: och-quad
    const int mt = wave & 1;        // och tile (16 och)
    const int rbase = (wave >> 1) * 8;

    // per-thread granule coords, fixed across tiles
    int gw[9], gr[9], gq[9];
    #pragma unroll
    for (int it = 0; it < 9; ++it) {
        const int idx = it * 256 + t;
        gw[it] = idx % RCOLS;
        gr[it] = (idx / RCOLS) % RROWS;
        gq[it] = idx / (RCOLS * RROWS);
    }

    const bf16x8* __restrict__ Wpt = (const bf16x8*)W2g;
    float bb[4];
    #pragma unroll
    for (int reg = 0; reg < 4; reg++) bb[reg] = bias[mt * 16 + quad4 * 4 + reg];

    const volatile float* xv = x;   // volatile: pin load issue points
    float v[9][8];

    // stage tile gt into v (issue-only; waits happen at pack)
#define STAGE(gt)                                                              \
    {                                                                          \
        const int wb_ = (gt) % 12, hb_ = ((gt) / 12) % 12, n_ = (gt) / 144;    \
        const int row0_ = hb_ * HT - PADI, col0_ = wb_ * WTL - PADI;           \
        const volatile float* xn_ = xv + (size_t)n_ * CIN * H * W;             \
        _Pragma("unroll")                                                      \
        for (int it = 0; it < 9; ++it) {                                       \
            const int row = row0_ + gr[it], col = col0_ + gw[it];              \
            _Pragma("unroll")                                                  \
            for (int k = 0; k < 8; k++) v[it][k] = 0.0f;                       \
            if ((unsigned)row < (unsigned)H && (unsigned)col < (unsigned)W) {  \
                const volatile float* p =                                      \
                    xn_ + ((size_t)(gq[it] * 8) * H + row) * W + col;          \
                _Pragma("unroll")                                              \
                for (int k = 0; k < 8; k++) v[it][k] = p[(size_t)k * H * W];   \
            }                                                                  \
        }                                                                      \
    }

    STAGE(t0);   // prologue: tile 0 (only exposed staging)

    for (int i = 0; i < cnt; ++i) {
        const int g = t0 + i;
        const int wb = g % 12, hb = (g / 12) % 12, n = g / 144;

        // ---- pack staged regs -> LDS (waits vmcnt here) ----
        #pragma unroll
        for (int it = 0; it < 9; ++it) {
            const int idx = it * 256 + t;
            unsigned int d[4];
            #pragma unroll
            for (int k = 0; k < 4; k++)
                d[k] = cvtpk_bf16(v[it][2 * k], v[it][2 * k + 1]);
            *(uint4*)&ldsx[(size_t)idx * 8] = make_uint4(d[0], d[1], d[2], d[3]);
        }

        // A-preload for dx=0 (hides under the barrier)
        bf16x8 A[2][9];
        #pragma unroll
        for (int dy = 0; dy < 9; dy++)
            A[0][dy] = Wpt[((mt * 81 + dy * 9 + 0) * 4 + quad4) * 16 + l15];

        __syncthreads();   // LDS tile visible to all waves

        // ---- T14: issue NEXT tile's loads; latency hides under compute ----
        if (i + 1 < cnt) STAGE(g + 1);

        f32x4 acc[8];
        #pragma unroll
        for (int j = 0; j < 8; j++)
            acc[j] = (f32x4){bb[0], bb[1], bb[2], bb[3]};

        const unsigned short* bptr =
            &ldsx[(size_t)(((quad4 * RROWS + rbase) * RCOLS) + l15) * 8];

        #pragma unroll
        for (int dx = 0; dx < 9; dx++) {
            const int cur = dx & 1, nxt = cur ^ 1;
            if (dx < 8) {
                #pragma unroll
                for (int dy = 0; dy < 9; dy++)
                    A[nxt][dy] = Wpt[((mt * 81 + dy * 9 + (dx + 1)) * 4 + quad4) * 16 + l15];
            }
            __builtin_amdgcn_s_setprio(1);
            #pragma unroll
            for (int rr = 0; rr < 16; rr++) {       // lds row rel to rbase; out_r = rr - dy
                const bf16x8 bfrag = *(const bf16x8*)&bptr[(size_t)(rr * RCOLS + dx) * 8];
                #pragma unroll
                for (int dy = 0; dy < 9; dy++) {
                    const int orr = rr - dy;
                    if (orr >= 0 && orr < 8) {
                        acc[orr] = __builtin_amdgcn_mfma_f32_16x16x32_bf16(
                            A[cur][dy], bfrag, acc[orr], 0, 0, 0);
                    }
                }
            }
            __builtin_amdgcn_s_setprio(0);
        }

        // ---- epilogue: D col = lane&15 (pixel), row = quad4*4 + reg (och) ----
        float* outn = out + (size_t)n * NOUT * H * W;
        #pragma unroll
        for (int orr = 0; orr < 8; orr++) {
            const int row = hb * HT + rbase + orr;
            const int col = wb * WTL + l15;
            #pragma unroll
            for (int reg = 0; reg < 4; reg++) {
                const int och = mt * 16 + quad4 * 4 + reg;
                outn[((size_t)och * H + row) * W + col] = acc[orr][reg];
            }
        }

        __syncthreads();   // all waves done reading LDS before next pack overwrites
    }
#undef STAGE
}

extern "C" void kernel_launch(void* const* d_in, const int* in_sizes, int n_in,
                              void* d_out, int out_size, void* d_ws, size_t ws_size,
                              hipStream_t stream) {
    const float* x    = (const float*)d_in[0];
    const float* wp   = (const float*)d_in[1];   // (32,32,3)
    const float* bias = (const float*)d_in[2];   // (32,)
    float* out = (float*)d_out;
    unsigned short* W2g = (unsigned short*)d_ws; // 165,888 B of scratch

    genw_kernel<<<NOUT * CIN, 128, 0, stream>>>(wp, W2g);
    conv_kernel<<<NBLK, 256, 0, stream>>>(x, W2g, bias, out);
}